// Round 1
// baseline (13.762 us; speedup 1.0000x reference)
//
#include <hip/hip_runtime.h>

// logistic_fun: out[n] = sigmoid( sum_p w[p] * prod_j Xp[n, comb_idx[p, j]] )
// with D=16, M=3, p=969 monomials in combinations_with_replacement order:
//   [()] ++ [(i)] ++ [(i,j) i<=j] ++ [(i,j,k) i<=j<=k], all lexicographic.
// Evaluated as a nested Horner sum: 969 FMAs per row, all weight indices
// compile-time constants (running counters fold after full unroll).

constexpr int FD = 16;

__global__ __launch_bounds__(256) void poly_logit_kernel(
    const float* __restrict__ X,   // [n, 16]
    const float* __restrict__ w,   // [969]
    float* __restrict__ out,       // [n]
    int n)
{
    const int row = blockIdx.x * 256 + threadIdx.x;
    if (row >= n) return;

    // Load this row's 16 features into registers (4x float4).
    float x[FD];
    const float4* xv = reinterpret_cast<const float4*>(X + (size_t)row * FD);
    #pragma unroll
    for (int q = 0; q < FD / 4; ++q) {
        float4 v = xv[q];
        x[q * 4 + 0] = v.x;
        x[q * 4 + 1] = v.y;
        x[q * 4 + 2] = v.z;
        x[q * 4 + 3] = v.w;
    }

    // Horner-nested polynomial evaluation.
    // w layout: [0]=order-0 | [1..16]=order-1 | [17..152]=order-2 | [153..968]=order-3
    float logit = w[0];
    int c2 = 1 + FD;                        // 17
    int c3 = 1 + FD + (FD * (FD + 1)) / 2;  // 153

    // Constant-bound loops + folding guards so LLVM fully unrolls innermost
    // first (trip count 16 always), then guards/counters constant-fold.
    #pragma unroll
    for (int i = 0; i < FD; ++i) {
        float acc_i = w[1 + i];
        #pragma unroll
        for (int j = 0; j < FD; ++j) {
            if (j < i) continue;
            float acc_ij = w[c2++];
            #pragma unroll
            for (int k = 0; k < FD; ++k) {
                if (k < j) continue;
                acc_ij = fmaf(x[k], w[c3++], acc_ij);
            }
            acc_i = fmaf(x[j], acc_ij, acc_i);
        }
        logit = fmaf(x[i], acc_i, logit);
    }

    out[row] = 1.0f / (1.0f + __expf(-logit));
}

extern "C" void kernel_launch(void* const* d_in, const int* in_sizes, int n_in,
                              void* d_out, int out_size, void* d_ws, size_t ws_size,
                              hipStream_t stream) {
    const float* X = (const float*)d_in[0];
    const float* w = (const float*)d_in[1];
    // d_in[2] (comb_idx) is implicit: its structure is deterministic
    // (combinations_with_replacement(range(16), 0..3)) and hardcoded above.
    float* out = (float*)d_out;
    const int n = out_size;  // 65536 rows
    poly_logit_kernel<<<(n + 255) / 256, 256, 0, stream>>>(X, w, out, n);
}

// Round 2
// 9.785 us; speedup vs baseline: 1.4065x; 1.4065x over previous
//
#include <hip/hip_runtime.h>

// logistic_fun: out[n] = sigmoid( sum_p w[p] * prod over comb_idx[p] of X )
// D=16, M=3, p=969 monomials in combinations_with_replacement lexicographic
// order. Evaluated as nested Horner sums with closed-form compile-time weight
// indices. Monomial space split 4 ways (by first index i, pair-balanced) across
// the 4 waves of each block -> 2 waves/SIMD; 2 rows/thread for ILP and 2x
// scalar-load amortization. Partials combined in LDS, sigmoid fused.

constexpr int FD = 16;

// # of order-2 combos (a,b), a<=b, with first index a < i
__device__ __forceinline__ constexpr int F2(int i) { return i * FD - i * (i - 1) / 2; }
// sum of triangular numbers: T3(n) = n(n+1)(n+2)/6
__device__ __forceinline__ constexpr int T3(int n) { return n * (n + 1) * (n + 2) / 6; }

// Global w index of each monomial (lexicographic CWR order):
__device__ __forceinline__ constexpr int IDX1(int i) { return 1 + i; }
__device__ __forceinline__ constexpr int IDX2(int i, int j) { return 1 + FD + F2(i) + (j - i); }
__device__ __forceinline__ constexpr int IDX3(int i, int j, int k) {
    // 153 = 1 + 16 + 136 ; 816 = T3(16) = total # of order-3 combos
    return 153 + (816 - T3(FD - i)) + (F2(j) - F2(i)) + (k - j);
}

// Which split owns first-index i. Sets: S0={0,7,8,15} S1={1,6,9,14}
// S2={2,5,10,13} S3={3,4,11,12} -> FMA costs 256/244/236/232.
template <int S>
__device__ __forceinline__ void eval_split(const float* __restrict__ w,
                                           const float x0[FD], const float x1[FD],
                                           float& l0, float& l1) {
    constexpr int OWNER[FD] = {0, 1, 2, 3, 3, 2, 1, 0, 0, 1, 2, 3, 3, 2, 1, 0};
    if (S == 0) {  // order-0 term
        float w0 = w[0];
        l0 += w0;
        l1 += w0;
    }
    #pragma unroll
    for (int i = 0; i < FD; ++i) {
        if (OWNER[i] != S) continue;  // folds after unroll (S, i compile-time)
        float ai0 = w[IDX1(i)];
        float ai1 = ai0;
        #pragma unroll
        for (int j = 0; j < FD; ++j) {
            if (j < i) continue;
            float aij0 = w[IDX2(i, j)];
            float aij1 = aij0;
            #pragma unroll
            for (int k = 0; k < FD; ++k) {
                if (k < j) continue;
                float w3 = w[IDX3(i, j, k)];
                aij0 = fmaf(x0[k], w3, aij0);
                aij1 = fmaf(x1[k], w3, aij1);
            }
            ai0 = fmaf(x0[j], aij0, ai0);
            ai1 = fmaf(x1[j], aij1, ai1);
        }
        l0 = fmaf(x0[i], ai0, l0);
        l1 = fmaf(x1[i], ai1, l1);
    }
}

__global__ __launch_bounds__(256) void poly_logit_kernel(
    const float* __restrict__ X,   // [n, 16]
    const float* __restrict__ w,   // [969]
    float* __restrict__ out,       // [n]
    int n)
{
    const int lane = threadIdx.x;        // 0..63
    const int wid  = threadIdx.y;        // 0..3 = monomial split
    const int base = blockIdx.x * 128;   // 128 rows per block
    // clamp for safety (n = 65536 is an exact multiple of 128)
    const int r0 = min(base + lane, n - 1);
    const int r1 = min(base + lane + 64, n - 1);

    float x0[FD], x1[FD];
    const float4* xv0 = reinterpret_cast<const float4*>(X + (size_t)r0 * FD);
    const float4* xv1 = reinterpret_cast<const float4*>(X + (size_t)r1 * FD);
    #pragma unroll
    for (int q = 0; q < FD / 4; ++q) {
        float4 a = xv0[q];
        x0[4 * q + 0] = a.x; x0[4 * q + 1] = a.y; x0[4 * q + 2] = a.z; x0[4 * q + 3] = a.w;
        float4 b = xv1[q];
        x1[4 * q + 0] = b.x; x1[4 * q + 1] = b.y; x1[4 * q + 2] = b.z; x1[4 * q + 3] = b.w;
    }

    float l0 = 0.0f, l1 = 0.0f;
    if      (wid == 0) eval_split<0>(w, x0, x1, l0, l1);
    else if (wid == 1) eval_split<1>(w, x0, x1, l0, l1);
    else if (wid == 2) eval_split<2>(w, x0, x1, l0, l1);
    else               eval_split<3>(w, x0, x1, l0, l1);

    __shared__ float part[4][128];
    part[wid][lane]      = l0;
    part[wid][lane + 64] = l1;
    __syncthreads();

    const int t = wid * 64 + lane;  // linear tid 0..255
    if (t < 128) {
        const int row = base + t;
        if (row < n) {
            float s = part[0][t] + part[1][t] + part[2][t] + part[3][t];
            out[row] = 1.0f / (1.0f + __expf(-s));
        }
    }
}

extern "C" void kernel_launch(void* const* d_in, const int* in_sizes, int n_in,
                              void* d_out, int out_size, void* d_ws, size_t ws_size,
                              hipStream_t stream) {
    const float* X = (const float*)d_in[0];
    const float* w = (const float*)d_in[1];
    // d_in[2] (comb_idx) is implicit: deterministic CWR(range(16), 0..3) order,
    // hardcoded via the closed-form IDX functions above.
    float* out = (float*)d_out;
    const int n = out_size;  // 65536 rows
    const int blocks = (n + 127) / 128;
    poly_logit_kernel<<<blocks, dim3(64, 4), 0, stream>>>(X, w, out, n);
}

// Round 3
// 9.744 us; speedup vs baseline: 1.4123x; 1.0041x over previous
//
#include <hip/hip_runtime.h>

// logistic_fun: out[n] = sigmoid( sum_p w[p] * prod over comb_idx[p] of X )
// D=16, M=3, p=969 monomials in combinations_with_replacement lexicographic
// order, evaluated as nested Horner sums with closed-form compile-time weight
// indices. Monomial space split 8 ways by first index (pair-balanced so
// same-SIMD wave pairs have ~equal cost), 2 rows/thread for ILP.
// 512 blocks x 512 threads = 4096 waves = 4 waves/SIMD.

constexpr int FD = 16;

// # of order-2 combos (a,b), a<=b, with first index a < i
__device__ __forceinline__ constexpr int F2(int i) { return i * FD - i * (i - 1) / 2; }
// sum of triangular numbers: T3(n) = n(n+1)(n+2)/6
__device__ __forceinline__ constexpr int T3(int n) { return n * (n + 1) * (n + 2) / 6; }

// Global w index of each monomial (lexicographic CWR order):
__device__ __forceinline__ constexpr int IDX1(int i) { return 1 + i; }
__device__ __forceinline__ constexpr int IDX2(int i, int j) { return 1 + FD + F2(i) + (j - i); }
__device__ __forceinline__ constexpr int IDX3(int i, int j, int k) {
    // 153 = 1 + 16 + 136 ; 816 = T3(16) = total # of order-3 combos
    return 153 + (816 - T3(FD - i)) + (F2(j) - F2(i)) + (k - j);
}

// Which wave (split) owns first-index i. Pairs {0,15},{1,14},... balanced so
// SIMD s (getting waves s and s+4) sees cost 257/244/236/232 FMAs.
// Per-wave FMA costs: 156,142,130,120,101,102,106,112.
__device__ __forceinline__ constexpr int OWNER(int i) {
    constexpr int own[FD] = {0, 1, 2, 3, 7, 6, 5, 4, 4, 5, 6, 7, 3, 2, 1, 0};
    return own[i];
}

template <int S>
__device__ __forceinline__ void eval_split(const float* __restrict__ w,
                                           const float x0[FD], const float x1[FD],
                                           float& l0, float& l1) {
    if (S == 4) {  // order-0 constant term -> lightest wave
        float w0 = w[0];
        l0 += w0;
        l1 += w0;
    }
    #pragma unroll
    for (int i = 0; i < FD; ++i) {
        if (OWNER(i) != S) continue;  // folds after unroll (S, i compile-time)
        float ai0 = w[IDX1(i)];
        float ai1 = ai0;
        #pragma unroll
        for (int j = 0; j < FD; ++j) {
            if (j < i) continue;
            float aij0 = w[IDX2(i, j)];
            float aij1 = aij0;
            #pragma unroll
            for (int k = 0; k < FD; ++k) {
                if (k < j) continue;
                float w3 = w[IDX3(i, j, k)];
                aij0 = fmaf(x0[k], w3, aij0);
                aij1 = fmaf(x1[k], w3, aij1);
            }
            ai0 = fmaf(x0[j], aij0, ai0);
            ai1 = fmaf(x1[j], aij1, ai1);
        }
        l0 = fmaf(x0[i], ai0, l0);
        l1 = fmaf(x1[i], ai1, l1);
    }
}

__global__ __launch_bounds__(512, 4) void poly_logit_kernel(
    const float* __restrict__ X,   // [n, 16]
    const float* __restrict__ w,   // [969]
    float* __restrict__ out,       // [n]
    int n)
{
    const int lane = threadIdx.x;        // 0..63
    const int wid  = threadIdx.y;        // 0..7 = monomial split
    const int base = blockIdx.x * 128;   // 128 rows per block
    // clamp for safety (n = 65536 is an exact multiple of 128)
    const int r0 = min(base + lane, n - 1);
    const int r1 = min(base + lane + 64, n - 1);

    float x0[FD], x1[FD];
    const float4* xv0 = reinterpret_cast<const float4*>(X + (size_t)r0 * FD);
    const float4* xv1 = reinterpret_cast<const float4*>(X + (size_t)r1 * FD);
    #pragma unroll
    for (int q = 0; q < FD / 4; ++q) {
        float4 a = xv0[q];
        x0[4 * q + 0] = a.x; x0[4 * q + 1] = a.y; x0[4 * q + 2] = a.z; x0[4 * q + 3] = a.w;
        float4 b = xv1[q];
        x1[4 * q + 0] = b.x; x1[4 * q + 1] = b.y; x1[4 * q + 2] = b.z; x1[4 * q + 3] = b.w;
    }

    float l0 = 0.0f, l1 = 0.0f;
    switch (wid) {  // wave-uniform branch
        case 0: eval_split<0>(w, x0, x1, l0, l1); break;
        case 1: eval_split<1>(w, x0, x1, l0, l1); break;
        case 2: eval_split<2>(w, x0, x1, l0, l1); break;
        case 3: eval_split<3>(w, x0, x1, l0, l1); break;
        case 4: eval_split<4>(w, x0, x1, l0, l1); break;
        case 5: eval_split<5>(w, x0, x1, l0, l1); break;
        case 6: eval_split<6>(w, x0, x1, l0, l1); break;
        default: eval_split<7>(w, x0, x1, l0, l1); break;
    }

    __shared__ float part[8][128];
    part[wid][lane]      = l0;
    part[wid][lane + 64] = l1;
    __syncthreads();

    const int t = wid * 64 + lane;  // linear tid 0..511
    if (t < 128) {
        const int row = base + t;
        if (row < n) {
            float s = (part[0][t] + part[1][t]) + (part[2][t] + part[3][t])
                    + (part[4][t] + part[5][t]) + (part[6][t] + part[7][t]);
            out[row] = 1.0f / (1.0f + __expf(-s));
        }
    }
}

extern "C" void kernel_launch(void* const* d_in, const int* in_sizes, int n_in,
                              void* d_out, int out_size, void* d_ws, size_t ws_size,
                              hipStream_t stream) {
    const float* X = (const float*)d_in[0];
    const float* w = (const float*)d_in[1];
    // d_in[2] (comb_idx) is implicit: deterministic CWR(range(16), 0..3) order,
    // hardcoded via the closed-form IDX functions above.
    float* out = (float*)d_out;
    const int n = out_size;  // 65536 rows
    const int blocks = (n + 127) / 128;
    poly_logit_kernel<<<blocks, dim3(64, 8), 0, stream>>>(X, w, out, n);
}